// Round 6
// baseline (351.980 us; speedup 1.0000x reference)
//
#include <hip/hip_runtime.h>
#include <hip/hip_bf16.h>

#define F_IN 128

typedef short bf16x8 __attribute__((ext_vector_type(8)));
typedef short bf16x4 __attribute__((ext_vector_type(4)));
typedef float f32x4  __attribute__((ext_vector_type(4)));
typedef float f32x2  __attribute__((ext_vector_type(2)));

// ---------------- CSR construction ----------------

__global__ void k_zero(int* __restrict__ p, int n) {
  int i = blockIdx.x * blockDim.x + threadIdx.x;
  if (i < n) p[i] = 0;
}

__global__ void k_count(const int* __restrict__ dst, int* __restrict__ cnt, int E) {
  int i = blockIdx.x * blockDim.x + threadIdx.x;
  if (i < E) atomicAdd(&cnt[dst[i]], 1);
}

__global__ void k_scan1(const int* __restrict__ cnt, int* __restrict__ rp,
                        int* __restrict__ bsum, float* __restrict__ dis,
                        int* __restrict__ fill, int n) {
  int tid = threadIdx.x;
  int i = blockIdx.x * 256 + tid;
  int v = (i < n) ? cnt[i] : 0;
  int orig = v;
  int lane = tid & 63;
  #pragma unroll
  for (int d = 1; d < 64; d <<= 1) {
    int t = __shfl_up(v, d);
    if (lane >= d) v += t;
  }
  __shared__ int wsum[4];
  int wid = tid >> 6;
  if (lane == 63) wsum[wid] = v;
  __syncthreads();
  int off = 0;
  for (int w = 0; w < wid; ++w) off += wsum[w];
  int incl = v + off;
  if (i < n) {
    rp[i]   = incl - orig;
    dis[i]  = rsqrtf(1.0f + (float)orig);
    fill[i] = 0;
  }
  if (tid == 255) bsum[blockIdx.x] = incl;
}

__global__ void k_scan2(int* __restrict__ bsum, int nb) {
  __shared__ int s[1024];
  int tid = threadIdx.x;
  int v = (tid < nb) ? bsum[tid] : 0;
  s[tid] = v;
  __syncthreads();
  for (int d = 1; d < 1024; d <<= 1) {
    int t = (tid >= d) ? s[tid - d] : 0;
    __syncthreads();
    s[tid] += t;
    __syncthreads();
  }
  if (tid < nb) bsum[tid] = s[tid] - v;
}

__global__ void k_scan3(int* __restrict__ rp, const int* __restrict__ bsum, int n, int E) {
  int i = blockIdx.x * blockDim.x + threadIdx.x;
  if (i < n) rp[i] += bsum[i >> 8];
  if (i == 0) rp[n] = E;
}

// packed (col, weight) per edge; pads cw[E..E+7] with zeros (read w=0 by tail lanes)
__global__ void k_fill_csr(const int* __restrict__ src, const int* __restrict__ dst,
                           const int* __restrict__ rp, int* __restrict__ fill,
                           const float* __restrict__ dis,
                           int2* __restrict__ cw, int E) {
  int e = blockIdx.x * blockDim.x + threadIdx.x;
  if (e < 8) cw[E + e] = make_int2(0, 0);
  if (e < E) {
    int s = src[e], d = dst[e];
    int pos = rp[d] + atomicAdd(&fill[d], 1);
    cw[pos] = make_int2(s, __float_as_int(dis[s] * dis[d]));
  }
}

// ---------------- gather+convert building_x[l2g] -> compact bf16 [n,128] ----------------

__global__ void k_tobf16(const float* __restrict__ X, const int* __restrict__ l2g,
                         ushort* __restrict__ out, int n) {
  int i = blockIdx.x * blockDim.x + threadIdx.x;   // one thread per 4 elems
  if (i >= n * 32) return;
  int row = i >> 5, c4 = (i & 31) * 4;
  int g = l2g[row];
  float4 v = *(const float4*)(X + (size_t)g * 128 + c4);
  ushort o[4];
  __hip_bfloat16 h;
  h = __float2bfloat16(v.x); o[0] = *(ushort*)&h;
  h = __float2bfloat16(v.y); o[1] = *(ushort*)&h;
  h = __float2bfloat16(v.z); o[2] = *(ushort*)&h;
  h = __float2bfloat16(v.w); o[3] = *(ushort*)&h;
  uint2 pk;
  pk.x = (uint)o[0] | ((uint)o[1] << 16);
  pk.y = (uint)o[2] | ((uint)o[3] << 16);
  *(uint2*)(out + (size_t)row * 128 + c4) = pk;
}

// ---------------- aggregation: 8 edges in flight/wave (8 groups x 8 lanes x 32B) -------
// One wave per node. Virtual edge t=-1 is the self-loop (weight dis^2). Edge indices
// are clamped (branch-free) and tail lanes masked with w=0; cw is padded so clamped
// reads are always in-bounds. Next iteration's cw record is prefetched before the
// row gather. FUSEW3 folds the tiny 128x2 GEMM into the epilogue (writes h3, not rows).

template <bool BIASRELU, bool FUSEW3>
__global__ void k_aggb(const ushort* __restrict__ X, const int* __restrict__ rp,
                       const int2* __restrict__ cw, const float* __restrict__ dis,
                       const float* __restrict__ bias, const float* __restrict__ W3,
                       ushort* __restrict__ outp, float* __restrict__ h3, int n) {
  int wavei = (int)((blockIdx.x * (size_t)blockDim.x + threadIdx.x) >> 6);
  int lane = threadIdx.x & 63;
  if (wavei >= n) return;
  int q = lane >> 3, ln = lane & 7;
  float d2 = dis[wavei]; d2 = d2 * d2;
  int e0 = rp[wavei], deg = rp[wavei + 1] - e0;
  int degm1 = deg - 1; if (degm1 < 0) degm1 = 0;

  f32x2 acc[8];
  #pragma unroll
  for (int j = 0; j < 8; ++j) acc[j] = f32x2{0.f, 0.f};

  int tq = q - 1;
  int idx0 = tq < 0 ? 0 : (tq > degm1 ? degm1 : tq);
  int2 c = cw[e0 + idx0];

  for (int t0 = -1; t0 < deg; t0 += 8) {
    // prefetch next iteration's edge record (independent of row gather)
    int tn = t0 + 8 + q;
    int idxn = tn > degm1 ? degm1 : tn;          // tn >= 7 so never < 0
    int2 cn = cw[e0 + idxn];

    int tc = t0 + q;
    int s  = tc < 0 ? wavei : c.x;
    float w = tc < 0 ? d2 : __int_as_float(c.y);
    w = tc < deg ? w : 0.0f;

    const char* rowp = (const char*)X + (((uint)s << 8) + ((uint)ln << 5));
    uint4 ra = *(const uint4*)rowp;
    uint4 rb = *(const uint4*)(rowp + 16);
    uint ua[8] = {ra.x, ra.y, ra.z, ra.w, rb.x, rb.y, rb.z, rb.w};
    f32x2 wv = {w, w};
    #pragma unroll
    for (int k = 0; k < 8; ++k) {
      f32x2 v;
      v.x = __uint_as_float(ua[k] << 16);
      v.y = __uint_as_float(ua[k] & 0xffff0000u);
      acc[k] += wv * v;
    }
    c = cn;
  }

  // reduce across the 8 groups (lane bits 3,4,5)
  #pragma unroll
  for (int j = 0; j < 8; ++j) {
    acc[j].x += __shfl_xor(acc[j].x, 8);
    acc[j].y += __shfl_xor(acc[j].y, 8);
    acc[j].x += __shfl_xor(acc[j].x, 16);
    acc[j].y += __shfl_xor(acc[j].y, 16);
    acc[j].x += __shfl_xor(acc[j].x, 32);
    acc[j].y += __shfl_xor(acc[j].y, 32);
  }

  if (lane < 8) {
    if (BIASRELU) {
      const float4* bp = (const float4*)(bias + ln * 16);
      #pragma unroll
      for (int j = 0; j < 4; ++j) {
        float4 b4 = bp[j];
        acc[2 * j].x     = fmaxf(acc[2 * j].x + b4.x, 0.f);
        acc[2 * j].y     = fmaxf(acc[2 * j].y + b4.y, 0.f);
        acc[2 * j + 1].x = fmaxf(acc[2 * j + 1].x + b4.z, 0.f);
        acc[2 * j + 1].y = fmaxf(acc[2 * j + 1].y + b4.w, 0.f);
      }
    }
    if (FUSEW3) {
      // h3[i] = row @ W3 ; lane ln covers features ln*16..ln*16+15
      const float4* w3p = (const float4*)(W3 + ln * 32);
      float p0 = 0.f, p1 = 0.f;
      #pragma unroll
      for (int j = 0; j < 8; ++j) {
        float4 wa = w3p[j];
        p0 = fmaf(acc[j].x, wa.x, p0);
        p1 = fmaf(acc[j].x, wa.y, p1);
        p0 = fmaf(acc[j].y, wa.z, p0);
        p1 = fmaf(acc[j].y, wa.w, p1);
      }
      p0 += __shfl_xor(p0, 1); p1 += __shfl_xor(p1, 1);
      p0 += __shfl_xor(p0, 2); p1 += __shfl_xor(p1, 2);
      p0 += __shfl_xor(p0, 4); p1 += __shfl_xor(p1, 4);
      if (ln == 0) {
        float2 r = make_float2(p0, p1);
        *(float2*)(h3 + (size_t)wavei * 2) = r;
      }
    } else {
      uint pk[8];
      #pragma unroll
      for (int j = 0; j < 8; ++j) {
        __hip_bfloat16 hx = __float2bfloat16(acc[j].x);
        __hip_bfloat16 hy = __float2bfloat16(acc[j].y);
        pk[j] = (uint)(*(ushort*)&hx) | ((uint)(*(ushort*)&hy) << 16);
      }
      char* op = (char*)outp + (((size_t)wavei << 8) + ((uint)ln << 5));
      uint4 s0 = make_uint4(pk[0], pk[1], pk[2], pk[3]);
      uint4 s1 = make_uint4(pk[4], pk[5], pk[6], pk[7]);
      *(uint4*)op = s0;
      *(uint4*)(op + 16) = s1;
    }
  }
}

// ---------------- W -> fragment-major bf16 repack ----------------
// lane l holds W[k = kt*32 + (l>>4)*4 + (j&3) + 16*(j>>2)][col = nt*16 + (l&15)]

template <int KT, int NT>
__global__ void k_prep_w(const float* __restrict__ W, ushort* __restrict__ WF) {
  int tid = blockIdx.x * 256 + threadIdx.x;
  if (tid >= KT * NT * 64) return;
  int l  = tid & 63;
  int nt = (tid >> 6) % NT;
  int kt = tid / (64 * NT);
  int colc = nt * 16 + (l & 15);
  int kbase = kt * 32 + (l >> 4) * 4;
  ushort v[8];
  #pragma unroll
  for (int j = 0; j < 8; ++j) {
    int k = kbase + (j & 3) + 16 * (j >> 2);
    __hip_bfloat16 h = __float2bfloat16(W[(size_t)k * (NT * 16) + colc]);
    v[j] = *(ushort*)&h;
  }
  uint4 pk;
  pk.x = (uint)v[0] | ((uint)v[1] << 16);
  pk.y = (uint)v[2] | ((uint)v[3] << 16);
  pk.z = (uint)v[4] | ((uint)v[5] << 16);
  pk.w = (uint)v[6] | ((uint)v[7] << 16);
  *(uint4*)(WF + (size_t)tid * 8) = pk;
}

// ---------------- wave-N-specialized MFMA GEMM ----------------
// Block = 256 threads (4 waves), BM = 128 rows. Wave w owns its N-slice and preloads
// its W fragments into registers. mfma(A=Wfrag, B=Xfrag): lane&15 = X-row,
// (lane>>4)*4+reg = output features -> packed 8B bf16 stores.

template <int KT, int NTW, bool OUTBF16, bool BIASRELU>
__global__ __launch_bounds__(256) void k_gemm_wspec(const ushort* __restrict__ A,
                                                    const ushort* __restrict__ WF,
                                                    const float* __restrict__ bias,
                                                    void* __restrict__ Cout, int n) {
  constexpr int K   = KT * 32;
  constexpr int NT  = NTW * 4;
  constexpr int N   = NT * 16;
  constexpr int CPR = K / 8;                   // 16B chunks per row
  __shared__ short lds[128 * CPR * 8];

  int tid = threadIdx.x;
  int r0 = blockIdx.x * 128;
  int l  = tid & 63;
  int w  = tid >> 6;
  int hi = l >> 4;

  // preload this wave's W-slice into registers (independent of LDS staging)
  bf16x8 wreg[KT * NTW];
  #pragma unroll
  for (int kt = 0; kt < KT; ++kt)
    #pragma unroll
    for (int nt = 0; nt < NTW; ++nt)
      wreg[kt * NTW + nt] =
          *(const bf16x8*)(WF + ((size_t)(kt * NT + w * NTW + nt) * 64 + l) * 8);

  // bias for this wave's feature slice
  float4 bb[NTW];
  if (BIASRELU) {
    #pragma unroll
    for (int nt = 0; nt < NTW; ++nt)
      bb[nt] = *(const float4*)(bias + (w * NTW + nt) * 16 + hi * 4);
  }

  // stage A tile (coalesced 16B loads, XOR-swizzled 16B chunks)
  #pragma unroll
  for (int p = 0; p < (128 * CPR) / 256; ++p) {
    int idx = p * 256 + tid;
    int row = idx / CPR, c = idx % CPR;
    uint4 v = make_uint4(0u, 0u, 0u, 0u);
    if (r0 + row < n) v = *(const uint4*)(A + (size_t)(r0 + row) * K + c * 8);
    *(uint4*)(&lds[row * CPR * 8 + ((c ^ (row & 15))) * 8]) = v;
  }
  __syncthreads();

  int sw = l & 15;
  #pragma unroll
  for (int s = 0; s < 8; ++s) {
    int rowl = s * 16 + (l & 15);
    bf16x8 xf[KT];
    #pragma unroll
    for (int kt = 0; kt < KT; ++kt) {
      int c0 = kt * 4 + (hi >> 1);
      int within = (hi & 1) * 4;
      bf16x4 lo = *(const bf16x4*)(&lds[rowl * CPR * 8 + (c0 ^ sw) * 8 + within]);
      bf16x4 hx = *(const bf16x4*)(&lds[rowl * CPR * 8 + ((c0 + 2) ^ sw) * 8 + within]);
      bf16x8 a;
      a[0] = lo[0]; a[1] = lo[1]; a[2] = lo[2]; a[3] = lo[3];
      a[4] = hx[0]; a[5] = hx[1]; a[6] = hx[2]; a[7] = hx[3];
      xf[kt] = a;
    }

    f32x4 acc[NTW];
    #pragma unroll
    for (int nt = 0; nt < NTW; ++nt) acc[nt] = f32x4{0.f, 0.f, 0.f, 0.f};
    #pragma unroll
    for (int nt = 0; nt < NTW; ++nt)
      #pragma unroll
      for (int kt = 0; kt < KT; ++kt)
        acc[nt] = __builtin_amdgcn_mfma_f32_16x16x32_bf16(wreg[kt * NTW + nt], xf[kt],
                                                          acc[nt], 0, 0, 0);

    int grow = r0 + s * 16 + (l & 15);
    if (grow < n) {
      #pragma unroll
      for (int nt = 0; nt < NTW; ++nt) {
        int f0 = (w * NTW + nt) * 16 + hi * 4;
        float v0 = acc[nt][0], v1 = acc[nt][1], v2 = acc[nt][2], v3 = acc[nt][3];
        if (BIASRELU) {
          v0 = fmaxf(v0 + bb[nt].x, 0.0f);
          v1 = fmaxf(v1 + bb[nt].y, 0.0f);
          v2 = fmaxf(v2 + bb[nt].z, 0.0f);
          v3 = fmaxf(v3 + bb[nt].w, 0.0f);
        }
        if (OUTBF16) {
          ushort o[4];
          __hip_bfloat16 h;
          h = __float2bfloat16(v0); o[0] = *(ushort*)&h;
          h = __float2bfloat16(v1); o[1] = *(ushort*)&h;
          h = __float2bfloat16(v2); o[2] = *(ushort*)&h;
          h = __float2bfloat16(v3); o[3] = *(ushort*)&h;
          uint2 pk;
          pk.x = (uint)o[0] | ((uint)o[1] << 16);
          pk.y = (uint)o[2] | ((uint)o[3] << 16);
          *(uint2*)((ushort*)Cout + (size_t)grow * N + f0) = pk;
        } else {
          f32x4 pk = {v0, v1, v2, v3};
          *(f32x4*)((float*)Cout + (size_t)grow * N + f0) = pk;
        }
      }
    }
  }
}

// ---------------- output ----------------

__global__ void k_fillout(float* __restrict__ out, int total) {
  int i = blockIdx.x * blockDim.x + threadIdx.x;
  if (i < total) out[i] = -0.69314718055994531f;
}

__global__ void k_agg3(const float* __restrict__ h3, const int* __restrict__ rp,
                       const int2* __restrict__ cw, const float* __restrict__ dis,
                       const float* __restrict__ b3, const int* __restrict__ l2g,
                       float* __restrict__ out, int n) {
  int i = blockIdx.x * blockDim.x + threadIdx.x;
  if (i >= n) return;
  float d2 = dis[i] * dis[i];
  float a0 = d2 * h3[(size_t)i * 2 + 0];
  float a1 = d2 * h3[(size_t)i * 2 + 1];
  int e0 = rp[i], e1 = rp[i + 1];
  for (int e = e0; e < e1; ++e) {
    int2 c = cw[e];
    float w = __int_as_float(c.y);
    a0 = fmaf(w, h3[(size_t)c.x * 2 + 0], a0);
    a1 = fmaf(w, h3[(size_t)c.x * 2 + 1], a1);
  }
  a0 += b3[0];
  a1 += b3[1];
  float m = fmaxf(a0, a1);
  float lse = m + logf(expf(a0 - m) + expf(a1 - m));
  int g = l2g[i];
  out[(size_t)g * 2 + 0] = a0 - lse;
  out[(size_t)g * 2 + 1] = a1 - lse;
}

// ---------------- launch ----------------

extern "C" void kernel_launch(void* const* d_in, const int* in_sizes, int n_in,
                              void* d_out, int out_size, void* d_ws, size_t ws_size,
                              hipStream_t stream) {
  const float* building_x = (const float*)d_in[0];
  const int*   l2g        = (const int*)d_in[1];
  const int*   esrc       = (const int*)d_in[2];
  const int*   edst       = (const int*)d_in[3];
  const float* W1 = (const float*)d_in[4];
  const float* b1 = (const float*)d_in[5];
  const float* W2 = (const float*)d_in[6];
  const float* b2 = (const float*)d_in[7];
  const float* W3 = (const float*)d_in[8];
  const float* b3 = (const float*)d_in[9];
  float* out = (float*)d_out;

  const int n_total = in_sizes[0] / F_IN;
  const int n_sub   = in_sizes[1];
  const int E       = in_sizes[2];
  const int nb      = (n_sub + 255) / 256;

  // ---- workspace (bf16 128-wide tensors, aliasing across phases) ----
  // xsub: input bf16 table (dead after agg1); xt: agg1 out (dead after gemm1,
  // reused by h2b); x1: gemm1 out.
  char* base = (char*)d_ws;
  auto al = [](size_t x) { return (x + 255) & ~(size_t)255; };
  size_t t128 = al((size_t)n_sub * 128 * 2);
  ushort* xsub = (ushort*)base;
  ushort* xt   = (ushort*)(base + t128);
  ushort* x1   = (ushort*)(base + 2 * t128);
  ushort* h2b  = xt;
  size_t off = 2 * t128 + al((size_t)n_sub * 256 * 2);
  auto alloc = [&](size_t bytes) -> void* {
    void* p = base + off;
    off += al(bytes);
    return p;
  };
  float* h3   = (float*)alloc((size_t)n_sub * 2 * 4);
  int*   cnt  = (int*)alloc((size_t)n_sub * 4);
  int*   fill = (int*)alloc((size_t)n_sub * 4);
  int*   rp   = (int*)alloc((size_t)(n_sub + 1) * 4);
  float* dis  = (float*)alloc((size_t)n_sub * 4);
  int2*  cw   = (int2*)alloc((size_t)(E + 8) * 8);
  int*   bsum = (int*)alloc((size_t)nb * 4);
  ushort* w1f = (ushort*)alloc((size_t)128 * 256 * 2);
  ushort* w2f = (ushort*)alloc((size_t)256 * 128 * 2);
  (void)ws_size; (void)n_in; (void)out_size;

  const int B = 256;

  // weight repack + input bf16 conversion (independent of CSR)
  k_prep_w<4, 16><<<16, 256, 0, stream>>>(W1, w1f);
  k_prep_w<8, 8><<<16, 256, 0, stream>>>(W2, w2f);
  k_tobf16<<<(n_sub * 32 + B - 1) / B, B, 0, stream>>>(building_x, l2g, xsub, n_sub);

  // CSR build
  k_zero<<<(n_sub + B - 1) / B, B, 0, stream>>>(cnt, n_sub);
  k_count<<<(E + B - 1) / B, B, 0, stream>>>(edst, cnt, E);
  k_scan1<<<nb, 256, 0, stream>>>(cnt, rp, bsum, dis, fill, n_sub);
  k_scan2<<<1, 1024, 0, stream>>>(bsum, nb);
  k_scan3<<<(n_sub + B - 1) / B, B, 0, stream>>>(rp, bsum, n_sub, E);
  k_fill_csr<<<(E + B - 1) / B, B, 0, stream>>>(esrc, edst, rp, fill, dis, cw, E);

  int aggBlocks  = (n_sub + 3) / 4;       // 4 waves / 256-thread block
  int gemmBlocks = (n_sub + 127) / 128;   // BM=128

  // Layer 1: aggregate (bf16 gather) -> bf16 xt, MFMA GEMM + bias + relu -> bf16 x1
  k_aggb<false, false><<<aggBlocks, B, 0, stream>>>(xsub, rp, cw, dis, nullptr, nullptr,
                                                    xt, nullptr, n_sub);
  k_gemm_wspec<4, 4, true, true><<<gemmBlocks, 256, 0, stream>>>(xt, w1f, b1, x1, n_sub);

  // Layer 2: MFMA GEMM (x1 @ W2) -> bf16 h2b, then fused aggregate+bias+relu+W3 -> h3
  k_gemm_wspec<8, 2, true, false><<<gemmBlocks, 256, 0, stream>>>(x1, w2f, nullptr, h2b, n_sub);
  k_aggb<true, true><<<aggBlocks, B, 0, stream>>>(h2b, rp, cw, dis, b2, W3,
                                                  nullptr, h3, n_sub);

  // Layer 3: fill output, aggregate h3 + bias + log_softmax scatter
  k_fillout<<<(2 * n_total + B - 1) / B, B, 0, stream>>>(out, 2 * n_total);
  k_agg3<<<(n_sub + B - 1) / B, B, 0, stream>>>(h3, rp, cw, dis, b3, l2g, out, n_sub);
}

// Round 7
// 316.997 us; speedup vs baseline: 1.1104x; 1.1104x over previous
//
#include <hip/hip_runtime.h>
#include <hip/hip_bf16.h>

#define F_IN 128

typedef short bf16x8 __attribute__((ext_vector_type(8)));
typedef short bf16x4 __attribute__((ext_vector_type(4)));
typedef float f32x4  __attribute__((ext_vector_type(4)));

// ---------------- CSR construction ----------------

__global__ void k_zero(int* __restrict__ p, int n) {
  int i = blockIdx.x * blockDim.x + threadIdx.x;
  if (i < n) p[i] = 0;
}

__global__ void k_count(const int* __restrict__ dst, int* __restrict__ cnt, int E) {
  int i = blockIdx.x * blockDim.x + threadIdx.x;
  if (i < E) atomicAdd(&cnt[dst[i]], 1);
}

__global__ void k_scan1(const int* __restrict__ cnt, int* __restrict__ rp,
                        int* __restrict__ bsum, float* __restrict__ dis,
                        int* __restrict__ fill, int n) {
  int tid = threadIdx.x;
  int i = blockIdx.x * 256 + tid;
  int v = (i < n) ? cnt[i] : 0;
  int orig = v;
  int lane = tid & 63;
  #pragma unroll
  for (int d = 1; d < 64; d <<= 1) {
    int t = __shfl_up(v, d);
    if (lane >= d) v += t;
  }
  __shared__ int wsum[4];
  int wid = tid >> 6;
  if (lane == 63) wsum[wid] = v;
  __syncthreads();
  int off = 0;
  for (int w = 0; w < wid; ++w) off += wsum[w];
  int incl = v + off;
  if (i < n) {
    rp[i]   = incl - orig;
    dis[i]  = rsqrtf(1.0f + (float)orig);
    fill[i] = 0;
  }
  if (tid == 255) bsum[blockIdx.x] = incl;
}

__global__ void k_scan2(int* __restrict__ bsum, int nb) {
  __shared__ int s[1024];
  int tid = threadIdx.x;
  int v = (tid < nb) ? bsum[tid] : 0;
  s[tid] = v;
  __syncthreads();
  for (int d = 1; d < 1024; d <<= 1) {
    int t = (tid >= d) ? s[tid - d] : 0;
    __syncthreads();
    s[tid] += t;
    __syncthreads();
  }
  if (tid < nb) bsum[tid] = s[tid] - v;
}

__global__ void k_scan3(int* __restrict__ rp, const int* __restrict__ bsum, int n, int E) {
  int i = blockIdx.x * blockDim.x + threadIdx.x;
  if (i < n) rp[i] += bsum[i >> 8];
  if (i == 0) rp[n] = E;
}

// packed (col, weight) per edge; pads cw[E..E+3] with zeros (clamped reads of deg-0 nodes)
__global__ void k_fill_csr(const int* __restrict__ src, const int* __restrict__ dst,
                           const int* __restrict__ rp, int* __restrict__ fill,
                           const float* __restrict__ dis,
                           int2* __restrict__ cw, int E) {
  int e = blockIdx.x * blockDim.x + threadIdx.x;
  if (e < 4) cw[E + e] = make_int2(0, 0);
  if (e < E) {
    int s = src[e], d = dst[e];
    int pos = rp[d] + atomicAdd(&fill[d], 1);
    cw[pos] = make_int2(s, __float_as_int(dis[s] * dis[d]));
  }
}

// ---------------- gather+convert building_x[l2g] -> compact bf16 [n,128] ----------------

__global__ void k_tobf16(const float* __restrict__ X, const int* __restrict__ l2g,
                         ushort* __restrict__ out, int n) {
  int i = blockIdx.x * blockDim.x + threadIdx.x;   // one thread per 4 elems
  if (i >= n * 32) return;
  int row = i >> 5, c4 = (i & 31) * 4;
  int g = l2g[row];
  float4 v = *(const float4*)(X + (size_t)g * 128 + c4);
  ushort o[4];
  __hip_bfloat16 h;
  h = __float2bfloat16(v.x); o[0] = *(ushort*)&h;
  h = __float2bfloat16(v.y); o[1] = *(ushort*)&h;
  h = __float2bfloat16(v.z); o[2] = *(ushort*)&h;
  h = __float2bfloat16(v.w); o[3] = *(ushort*)&h;
  uint2 pk;
  pk.x = (uint)o[0] | ((uint)o[1] << 16);
  pk.y = (uint)o[2] | ((uint)o[3] << 16);
  *(uint2*)(out + (size_t)row * 128 + c4) = pk;
}

// ---------------- aggregation: 4 groups x 16 lanes x 16B (proven geometry) ----------------
// One wave per node; group q handles edge t0+q (full 256B row via 16 lanes x 16B).
// Self-loop = virtual edge t=-1 (weight dis^2). Next iteration's cw record is
// prefetched (clamped within this node's edge range; cw padded for deg=0).
// FUSEW3 folds the 128x2 GEMM into the epilogue (writes h3[2] instead of the row).

template <bool BIASRELU, bool FUSEW3>
__global__ void k_aggb(const ushort* __restrict__ X, const int* __restrict__ rp,
                       const int2* __restrict__ cw, const float* __restrict__ dis,
                       const float* __restrict__ bias, const float* __restrict__ W3,
                       ushort* __restrict__ outp, float* __restrict__ h3, int n) {
  int wavei = (int)((blockIdx.x * (size_t)blockDim.x + threadIdx.x) >> 6);
  int lane = threadIdx.x & 63;
  if (wavei >= n) return;
  int q = lane >> 4, ln = lane & 15;
  float d2 = dis[wavei]; d2 = d2 * d2;
  int e0 = rp[wavei], deg = rp[wavei + 1] - e0;
  int degm1 = deg - 1; if (degm1 < 0) degm1 = 0;

  float acc[8];
  #pragma unroll
  for (int j = 0; j < 8; ++j) acc[j] = 0.0f;

  int tq = q - 1;
  int idx0 = tq < 0 ? 0 : (tq > degm1 ? degm1 : tq);
  int2 c = cw[e0 + idx0];

  for (int t0 = -1; t0 < deg; t0 += 4) {
    // prefetch next iteration's edge record (independent of the row gather)
    int tn = t0 + 4 + q;                         // >= 3, never negative
    int idxn = tn > degm1 ? degm1 : tn;
    int2 cn = cw[e0 + idxn];

    int tc = t0 + q;
    int s  = tc < 0 ? wavei : c.x;
    float w = tc < 0 ? d2 : __int_as_float(c.y);
    w = tc < deg ? w : 0.0f;

    uint4 r = *(const uint4*)((const char*)X + (((uint)s << 8) + ((uint)ln << 4)));
    uint u[4] = {r.x, r.y, r.z, r.w};
    #pragma unroll
    for (int tt = 0; tt < 4; ++tt) {
      float lo = __uint_as_float(u[tt] << 16);
      float hi = __uint_as_float(u[tt] & 0xffff0000u);
      acc[2 * tt]     = fmaf(w, lo, acc[2 * tt]);
      acc[2 * tt + 1] = fmaf(w, hi, acc[2 * tt + 1]);
    }
    c = cn;
  }

  // reduce across the 4 groups (lane bits 4,5)
  #pragma unroll
  for (int j = 0; j < 8; ++j) {
    acc[j] += __shfl_xor(acc[j], 16);
    acc[j] += __shfl_xor(acc[j], 32);
  }

  if (lane < 16) {
    if (BIASRELU) {
      float4 b0 = *(const float4*)(bias + ln * 8);
      float4 b1 = *(const float4*)(bias + ln * 8 + 4);
      float bb[8] = {b0.x, b0.y, b0.z, b0.w, b1.x, b1.y, b1.z, b1.w};
      #pragma unroll
      for (int j = 0; j < 8; ++j) acc[j] = fmaxf(acc[j] + bb[j], 0.0f);
    }
    if (FUSEW3) {
      // h3[i] = row @ W3 ; lane ln covers features ln*8..ln*8+7
      const float4* w3p = (const float4*)(W3 + ln * 16);
      float p0 = 0.f, p1 = 0.f;
      #pragma unroll
      for (int j2 = 0; j2 < 4; ++j2) {
        float4 wa = w3p[j2];
        p0 = fmaf(acc[2 * j2], wa.x, p0);
        p1 = fmaf(acc[2 * j2], wa.y, p1);
        p0 = fmaf(acc[2 * j2 + 1], wa.z, p0);
        p1 = fmaf(acc[2 * j2 + 1], wa.w, p1);
      }
      p0 += __shfl_xor(p0, 1); p1 += __shfl_xor(p1, 1);
      p0 += __shfl_xor(p0, 2); p1 += __shfl_xor(p1, 2);
      p0 += __shfl_xor(p0, 4); p1 += __shfl_xor(p1, 4);
      p0 += __shfl_xor(p0, 8); p1 += __shfl_xor(p1, 8);
      if (ln == 0) {
        float2 rr = make_float2(p0, p1);
        *(float2*)(h3 + (size_t)wavei * 2) = rr;
      }
    } else {
      uint pk[4];
      #pragma unroll
      for (int j2 = 0; j2 < 4; ++j2) {
        __hip_bfloat16 hx = __float2bfloat16(acc[2 * j2]);
        __hip_bfloat16 hy = __float2bfloat16(acc[2 * j2 + 1]);
        pk[j2] = (uint)(*(ushort*)&hx) | ((uint)(*(ushort*)&hy) << 16);
      }
      uint4 sv = make_uint4(pk[0], pk[1], pk[2], pk[3]);
      *(uint4*)((char*)outp + (((size_t)wavei << 8) + ((uint)ln << 4))) = sv;
    }
  }
}

// ---------------- W -> fragment-major bf16 repack ----------------
// lane l holds W[k = kt*32 + (l>>4)*4 + (j&3) + 16*(j>>2)][col = nt*16 + (l&15)]

template <int KT, int NT>
__global__ void k_prep_w(const float* __restrict__ W, ushort* __restrict__ WF) {
  int tid = blockIdx.x * 256 + threadIdx.x;
  if (tid >= KT * NT * 64) return;
  int l  = tid & 63;
  int nt = (tid >> 6) % NT;
  int kt = tid / (64 * NT);
  int colc = nt * 16 + (l & 15);
  int kbase = kt * 32 + (l >> 4) * 4;
  ushort v[8];
  #pragma unroll
  for (int j = 0; j < 8; ++j) {
    int k = kbase + (j & 3) + 16 * (j >> 2);
    __hip_bfloat16 h = __float2bfloat16(W[(size_t)k * (NT * 16) + colc]);
    v[j] = *(ushort*)&h;
  }
  uint4 pk;
  pk.x = (uint)v[0] | ((uint)v[1] << 16);
  pk.y = (uint)v[2] | ((uint)v[3] << 16);
  pk.z = (uint)v[4] | ((uint)v[5] << 16);
  pk.w = (uint)v[6] | ((uint)v[7] << 16);
  *(uint4*)(WF + (size_t)tid * 8) = pk;
}

// ---------------- wave-N-specialized MFMA GEMM ----------------
// Block = 256 threads (4 waves), BM = 128 rows. Wave w owns its N-slice and preloads
// its W fragments into registers. mfma(A=Wfrag, B=Xfrag): lane&15 = X-row,
// (lane>>4)*4+reg = output features -> packed 8B bf16 stores.

template <int KT, int NTW, bool OUTBF16, bool BIASRELU>
__global__ __launch_bounds__(256) void k_gemm_wspec(const ushort* __restrict__ A,
                                                    const ushort* __restrict__ WF,
                                                    const float* __restrict__ bias,
                                                    void* __restrict__ Cout, int n) {
  constexpr int K   = KT * 32;
  constexpr int NT  = NTW * 4;
  constexpr int N   = NT * 16;
  constexpr int CPR = K / 8;                   // 16B chunks per row
  __shared__ short lds[128 * CPR * 8];

  int tid = threadIdx.x;
  int r0 = blockIdx.x * 128;
  int l  = tid & 63;
  int w  = tid >> 6;
  int hi = l >> 4;

  // preload this wave's W-slice into registers (independent of LDS staging)
  bf16x8 wreg[KT * NTW];
  #pragma unroll
  for (int kt = 0; kt < KT; ++kt)
    #pragma unroll
    for (int nt = 0; nt < NTW; ++nt)
      wreg[kt * NTW + nt] =
          *(const bf16x8*)(WF + ((size_t)(kt * NT + w * NTW + nt) * 64 + l) * 8);

  // bias for this wave's feature slice
  float4 bb[NTW];
  if (BIASRELU) {
    #pragma unroll
    for (int nt = 0; nt < NTW; ++nt)
      bb[nt] = *(const float4*)(bias + (w * NTW + nt) * 16 + hi * 4);
  }

  // stage A tile (coalesced 16B loads, XOR-swizzled 16B chunks)
  #pragma unroll
  for (int p = 0; p < (128 * CPR) / 256; ++p) {
    int idx = p * 256 + tid;
    int row = idx / CPR, c = idx % CPR;
    uint4 v = make_uint4(0u, 0u, 0u, 0u);
    if (r0 + row < n) v = *(const uint4*)(A + (size_t)(r0 + row) * K + c * 8);
    *(uint4*)(&lds[row * CPR * 8 + ((c ^ (row & 15))) * 8]) = v;
  }
  __syncthreads();

  int sw = l & 15;
  #pragma unroll
  for (int s = 0; s < 8; ++s) {
    int rowl = s * 16 + (l & 15);
    bf16x8 xf[KT];
    #pragma unroll
    for (int kt = 0; kt < KT; ++kt) {
      int c0 = kt * 4 + (hi >> 1);
      int within = (hi & 1) * 4;
      bf16x4 lo = *(const bf16x4*)(&lds[rowl * CPR * 8 + (c0 ^ sw) * 8 + within]);
      bf16x4 hx = *(const bf16x4*)(&lds[rowl * CPR * 8 + ((c0 + 2) ^ sw) * 8 + within]);
      bf16x8 a;
      a[0] = lo[0]; a[1] = lo[1]; a[2] = lo[2]; a[3] = lo[3];
      a[4] = hx[0]; a[5] = hx[1]; a[6] = hx[2]; a[7] = hx[3];
      xf[kt] = a;
    }

    f32x4 acc[NTW];
    #pragma unroll
    for (int nt = 0; nt < NTW; ++nt) acc[nt] = f32x4{0.f, 0.f, 0.f, 0.f};
    #pragma unroll
    for (int nt = 0; nt < NTW; ++nt)
      #pragma unroll
      for (int kt = 0; kt < KT; ++kt)
        acc[nt] = __builtin_amdgcn_mfma_f32_16x16x32_bf16(wreg[kt * NTW + nt], xf[kt],
                                                          acc[nt], 0, 0, 0);

    int grow = r0 + s * 16 + (l & 15);
    if (grow < n) {
      #pragma unroll
      for (int nt = 0; nt < NTW; ++nt) {
        int f0 = (w * NTW + nt) * 16 + hi * 4;
        float v0 = acc[nt][0], v1 = acc[nt][1], v2 = acc[nt][2], v3 = acc[nt][3];
        if (BIASRELU) {
          v0 = fmaxf(v0 + bb[nt].x, 0.0f);
          v1 = fmaxf(v1 + bb[nt].y, 0.0f);
          v2 = fmaxf(v2 + bb[nt].z, 0.0f);
          v3 = fmaxf(v3 + bb[nt].w, 0.0f);
        }
        if (OUTBF16) {
          ushort o[4];
          __hip_bfloat16 h;
          h = __float2bfloat16(v0); o[0] = *(ushort*)&h;
          h = __float2bfloat16(v1); o[1] = *(ushort*)&h;
          h = __float2bfloat16(v2); o[2] = *(ushort*)&h;
          h = __float2bfloat16(v3); o[3] = *(ushort*)&h;
          uint2 pk;
          pk.x = (uint)o[0] | ((uint)o[1] << 16);
          pk.y = (uint)o[2] | ((uint)o[3] << 16);
          *(uint2*)((ushort*)Cout + (size_t)grow * N + f0) = pk;
        } else {
          f32x4 pk = {v0, v1, v2, v3};
          *(f32x4*)((float*)Cout + (size_t)grow * N + f0) = pk;
        }
      }
    }
  }
}

// ---------------- output ----------------

__global__ void k_fillout(float* __restrict__ out, int total) {
  int i = blockIdx.x * blockDim.x + threadIdx.x;
  if (i < total) out[i] = -0.69314718055994531f;
}

__global__ void k_agg3(const float* __restrict__ h3, const int* __restrict__ rp,
                       const int2* __restrict__ cw, const float* __restrict__ dis,
                       const float* __restrict__ b3, const int* __restrict__ l2g,
                       float* __restrict__ out, int n) {
  int i = blockIdx.x * blockDim.x + threadIdx.x;
  if (i >= n) return;
  float d2 = dis[i] * dis[i];
  float a0 = d2 * h3[(size_t)i * 2 + 0];
  float a1 = d2 * h3[(size_t)i * 2 + 1];
  int e0 = rp[i], e1 = rp[i + 1];
  for (int e = e0; e < e1; ++e) {
    int2 c = cw[e];
    float w = __int_as_float(c.y);
    a0 = fmaf(w, h3[(size_t)c.x * 2 + 0], a0);
    a1 = fmaf(w, h3[(size_t)c.x * 2 + 1], a1);
  }
  a0 += b3[0];
  a1 += b3[1];
  float m = fmaxf(a0, a1);
  float lse = m + logf(expf(a0 - m) + expf(a1 - m));
  int g = l2g[i];
  out[(size_t)g * 2 + 0] = a0 - lse;
  out[(size_t)g * 2 + 1] = a1 - lse;
}

// ---------------- launch ----------------

extern "C" void kernel_launch(void* const* d_in, const int* in_sizes, int n_in,
                              void* d_out, int out_size, void* d_ws, size_t ws_size,
                              hipStream_t stream) {
  const float* building_x = (const float*)d_in[0];
  const int*   l2g        = (const int*)d_in[1];
  const int*   esrc       = (const int*)d_in[2];
  const int*   edst       = (const int*)d_in[3];
  const float* W1 = (const float*)d_in[4];
  const float* b1 = (const float*)d_in[5];
  const float* W2 = (const float*)d_in[6];
  const float* b2 = (const float*)d_in[7];
  const float* W3 = (const float*)d_in[8];
  const float* b3 = (const float*)d_in[9];
  float* out = (float*)d_out;

  const int n_total = in_sizes[0] / F_IN;
  const int n_sub   = in_sizes[1];
  const int E       = in_sizes[2];
  const int nb      = (n_sub + 255) / 256;

  // ---- workspace (bf16 128-wide tensors, aliasing across phases) ----
  // xsub: input bf16 table (dead after agg1); xt: agg1 out (dead after gemm1,
  // reused by h2b); x1: gemm1 out.
  char* base = (char*)d_ws;
  auto al = [](size_t x) { return (x + 255) & ~(size_t)255; };
  size_t t128 = al((size_t)n_sub * 128 * 2);
  ushort* xsub = (ushort*)base;
  ushort* xt   = (ushort*)(base + t128);
  ushort* x1   = (ushort*)(base + 2 * t128);
  ushort* h2b  = xt;
  size_t off = 2 * t128 + al((size_t)n_sub * 256 * 2);
  auto alloc = [&](size_t bytes) -> void* {
    void* p = base + off;
    off += al(bytes);
    return p;
  };
  float* h3   = (float*)alloc((size_t)n_sub * 2 * 4);
  int*   cnt  = (int*)alloc((size_t)n_sub * 4);
  int*   fill = (int*)alloc((size_t)n_sub * 4);
  int*   rp   = (int*)alloc((size_t)(n_sub + 1) * 4);
  float* dis  = (float*)alloc((size_t)n_sub * 4);
  int2*  cw   = (int2*)alloc((size_t)(E + 4) * 8);
  int*   bsum = (int*)alloc((size_t)nb * 4);
  ushort* w1f = (ushort*)alloc((size_t)128 * 256 * 2);
  ushort* w2f = (ushort*)alloc((size_t)256 * 128 * 2);
  (void)ws_size; (void)n_in; (void)out_size;

  const int B = 256;

  // weight repack + input bf16 conversion (independent of CSR)
  k_prep_w<4, 16><<<16, 256, 0, stream>>>(W1, w1f);
  k_prep_w<8, 8><<<16, 256, 0, stream>>>(W2, w2f);
  k_tobf16<<<(n_sub * 32 + B - 1) / B, B, 0, stream>>>(building_x, l2g, xsub, n_sub);

  // CSR build
  k_zero<<<(n_sub + B - 1) / B, B, 0, stream>>>(cnt, n_sub);
  k_count<<<(E + B - 1) / B, B, 0, stream>>>(edst, cnt, E);
  k_scan1<<<nb, 256, 0, stream>>>(cnt, rp, bsum, dis, fill, n_sub);
  k_scan2<<<1, 1024, 0, stream>>>(bsum, nb);
  k_scan3<<<(n_sub + B - 1) / B, B, 0, stream>>>(rp, bsum, n_sub, E);
  k_fill_csr<<<(E + B - 1) / B, B, 0, stream>>>(esrc, edst, rp, fill, dis, cw, E);

  int aggBlocks  = (n_sub + 3) / 4;       // 4 waves / 256-thread block
  int gemmBlocks = (n_sub + 127) / 128;   // BM=128

  // Layer 1: aggregate (bf16 gather) -> bf16 xt, MFMA GEMM + bias + relu -> bf16 x1
  k_aggb<false, false><<<aggBlocks, B, 0, stream>>>(xsub, rp, cw, dis, nullptr, nullptr,
                                                    xt, nullptr, n_sub);
  k_gemm_wspec<4, 4, true, true><<<gemmBlocks, 256, 0, stream>>>(xt, w1f, b1, x1, n_sub);

  // Layer 2: MFMA GEMM (x1 @ W2) -> bf16 h2b, then fused aggregate+bias+relu+W3 -> h3
  k_gemm_wspec<8, 2, true, false><<<gemmBlocks, 256, 0, stream>>>(x1, w2f, nullptr, h2b, n_sub);
  k_aggb<true, true><<<aggBlocks, B, 0, stream>>>(h2b, rp, cw, dis, b2, W3,
                                                  nullptr, h3, n_sub);

  // Layer 3: fill output, aggregate h3 + bias + log_softmax scatter
  k_fillout<<<(2 * n_total + B - 1) / B, B, 0, stream>>>(out, 2 * n_total);
  k_agg3<<<(n_sub + B - 1) / B, B, 0, stream>>>(h3, rp, cw, dis, b3, l2g, out, n_sub);
}

// Round 8
// 305.407 us; speedup vs baseline: 1.1525x; 1.0379x over previous
//
#include <hip/hip_runtime.h>
#include <hip/hip_bf16.h>

#define F_IN 128

typedef short bf16x8 __attribute__((ext_vector_type(8)));
typedef short bf16x4 __attribute__((ext_vector_type(4)));
typedef float f32x4  __attribute__((ext_vector_type(4)));
typedef float f32x2  __attribute__((ext_vector_type(2)));

// ---------------- CSR construction (self-loops included: slot 0 of each row) ----------

__global__ void k_one(int* __restrict__ p, int n) {
  int i = blockIdx.x * blockDim.x + threadIdx.x;
  if (i < n) p[i] = 1;                    // self-loop pre-counted
}

__global__ void k_count(const int* __restrict__ dst, int* __restrict__ cnt, int E) {
  int i = blockIdx.x * blockDim.x + threadIdx.x;
  if (i < E) atomicAdd(&cnt[dst[i]], 1);
}

__global__ void k_scan1(const int* __restrict__ cnt, int* __restrict__ rp,
                        int* __restrict__ bsum, float* __restrict__ dis,
                        int* __restrict__ fill, int n) {
  int tid = threadIdx.x;
  int i = blockIdx.x * 256 + tid;
  int v = (i < n) ? cnt[i] : 0;
  int orig = v;
  int lane = tid & 63;
  #pragma unroll
  for (int d = 1; d < 64; d <<= 1) {
    int t = __shfl_up(v, d);
    if (lane >= d) v += t;
  }
  __shared__ int wsum[4];
  int wid = tid >> 6;
  if (lane == 63) wsum[wid] = v;
  __syncthreads();
  int off = 0;
  for (int w = 0; w < wid; ++w) off += wsum[w];
  int incl = v + off;
  if (i < n) {
    rp[i]   = incl - orig;
    dis[i]  = rsqrtf((float)orig);        // orig = 1 + in-degree
    fill[i] = 1;                          // slot 0 reserved for self
  }
  if (tid == 255) bsum[blockIdx.x] = incl;
}

__global__ void k_scan2(int* __restrict__ bsum, int nb) {
  __shared__ int s[1024];
  int tid = threadIdx.x;
  int v = (tid < nb) ? bsum[tid] : 0;
  s[tid] = v;
  __syncthreads();
  for (int d = 1; d < 1024; d <<= 1) {
    int t = (tid >= d) ? s[tid - d] : 0;
    __syncthreads();
    s[tid] += t;
    __syncthreads();
  }
  if (tid < nb) bsum[tid] = s[tid] - v;
}

__global__ void k_scan3(int* __restrict__ rp, const int* __restrict__ bsum, int n, int Etot) {
  int i = blockIdx.x * blockDim.x + threadIdx.x;
  if (i < n) rp[i] += bsum[i >> 8];
  if (i == 0) rp[n] = Etot;
}

// edges at slots >=1; self (i, dis_i^2) at slot 0
__global__ void k_fill_csr(const int* __restrict__ src, const int* __restrict__ dst,
                           const int* __restrict__ rp, int* __restrict__ fill,
                           const float* __restrict__ dis,
                           int2* __restrict__ cw, int E, int n) {
  int e = blockIdx.x * blockDim.x + threadIdx.x;
  if (e < n) {
    float d = dis[e];
    cw[rp[e]] = make_int2(e, __float_as_int(d * d));
  }
  if (e < E) {
    int s = src[e], d = dst[e];
    int pos = rp[d] + atomicAdd(&fill[d], 1);
    cw[pos] = make_int2(s, __float_as_int(dis[s] * dis[d]));
  }
}

// ---------------- gather+convert building_x[l2g] -> compact bf16 [n,128] ----------------

__global__ void k_tobf16(const float* __restrict__ X, const int* __restrict__ l2g,
                         ushort* __restrict__ out, int n) {
  int i = blockIdx.x * blockDim.x + threadIdx.x;   // one thread per 4 elems
  if (i >= n * 32) return;
  int row = i >> 5, c4 = (i & 31) * 4;
  int g = l2g[row];
  float4 v = *(const float4*)(X + (size_t)g * 128 + c4);
  ushort o[4];
  __hip_bfloat16 h;
  h = __float2bfloat16(v.x); o[0] = *(ushort*)&h;
  h = __float2bfloat16(v.y); o[1] = *(ushort*)&h;
  h = __float2bfloat16(v.z); o[2] = *(ushort*)&h;
  h = __float2bfloat16(v.w); o[3] = *(ushort*)&h;
  uint2 pk;
  pk.x = (uint)o[0] | ((uint)o[1] << 16);
  pk.y = (uint)o[2] | ((uint)o[3] << 16);
  *(uint2*)(out + (size_t)row * 128 + c4) = pk;
}

// ---------------- aggregation: 4 groups x 16 lanes x 16B, exec-masked tail -------------
// One wave per node; group q handles slot t0+q of the node's CSR row (self included
// as slot 0). Tail lanes are exec-masked: no gather traffic, no clamp arithmetic.
// FUSEW3 folds the 128x2 GEMM into the epilogue (writes h3[2] instead of the row).

template <bool BIASRELU, bool FUSEW3>
__global__ void k_aggb(const ushort* __restrict__ X, const int* __restrict__ rp,
                       const int2* __restrict__ cw, const float* __restrict__ bias,
                       const float* __restrict__ W3,
                       ushort* __restrict__ outp, float* __restrict__ h3, int n) {
  int wavei = (int)((blockIdx.x * (size_t)blockDim.x + threadIdx.x) >> 6);
  int lane = threadIdx.x & 63;
  if (wavei >= n) return;
  int q = lane >> 4, ln = lane & 15;
  int e0 = rp[wavei], deg = rp[wavei + 1] - e0;   // >= 1 (self)

  f32x2 acc[4];
  #pragma unroll
  for (int j = 0; j < 4; ++j) acc[j] = f32x2{0.f, 0.f};

  for (int t0 = 0; t0 < deg; t0 += 4) {
    int t = t0 + q;
    if (t < deg) {
      int2 c = cw[e0 + t];
      float w = __int_as_float(c.y);
      uint4 r = *(const uint4*)((const char*)X + (((uint)c.x << 8) + ((uint)ln << 4)));
      uint u[4] = {r.x, r.y, r.z, r.w};
      f32x2 wv = {w, w};
      #pragma unroll
      for (int tt = 0; tt < 4; ++tt) {
        f32x2 v;
        v.x = __uint_as_float(u[tt] << 16);
        v.y = __uint_as_float(u[tt] & 0xffff0000u);
        acc[tt] += wv * v;
      }
    }
  }

  // reduce across the 4 groups (lane bits 4,5)
  #pragma unroll
  for (int j = 0; j < 4; ++j) {
    acc[j].x += __shfl_xor(acc[j].x, 16);
    acc[j].y += __shfl_xor(acc[j].y, 16);
    acc[j].x += __shfl_xor(acc[j].x, 32);
    acc[j].y += __shfl_xor(acc[j].y, 32);
  }

  if (lane < 16) {
    if (BIASRELU) {
      float4 b0 = *(const float4*)(bias + ln * 8);
      float4 b1 = *(const float4*)(bias + ln * 8 + 4);
      acc[0].x = fmaxf(acc[0].x + b0.x, 0.f);
      acc[0].y = fmaxf(acc[0].y + b0.y, 0.f);
      acc[1].x = fmaxf(acc[1].x + b0.z, 0.f);
      acc[1].y = fmaxf(acc[1].y + b0.w, 0.f);
      acc[2].x = fmaxf(acc[2].x + b1.x, 0.f);
      acc[2].y = fmaxf(acc[2].y + b1.y, 0.f);
      acc[3].x = fmaxf(acc[3].x + b1.z, 0.f);
      acc[3].y = fmaxf(acc[3].y + b1.w, 0.f);
    }
    if (FUSEW3) {
      // h3[i] = row @ W3 ; lane ln covers features ln*8..ln*8+7
      const float4* w3p = (const float4*)(W3 + ln * 16);
      float p0 = 0.f, p1 = 0.f;
      #pragma unroll
      for (int j2 = 0; j2 < 4; ++j2) {
        float4 wa = w3p[j2];
        p0 = fmaf(acc[j2].x, wa.x, p0);
        p1 = fmaf(acc[j2].x, wa.y, p1);
        p0 = fmaf(acc[j2].y, wa.z, p0);
        p1 = fmaf(acc[j2].y, wa.w, p1);
      }
      p0 += __shfl_xor(p0, 1); p1 += __shfl_xor(p1, 1);
      p0 += __shfl_xor(p0, 2); p1 += __shfl_xor(p1, 2);
      p0 += __shfl_xor(p0, 4); p1 += __shfl_xor(p1, 4);
      p0 += __shfl_xor(p0, 8); p1 += __shfl_xor(p1, 8);
      if (ln == 0) {
        float2 rr = make_float2(p0, p1);
        *(float2*)(h3 + (size_t)wavei * 2) = rr;
      }
    } else {
      uint pk[4];
      #pragma unroll
      for (int j2 = 0; j2 < 4; ++j2) {
        __hip_bfloat16 hx = __float2bfloat16(acc[j2].x);
        __hip_bfloat16 hy = __float2bfloat16(acc[j2].y);
        pk[j2] = (uint)(*(ushort*)&hx) | ((uint)(*(ushort*)&hy) << 16);
      }
      uint4 sv = make_uint4(pk[0], pk[1], pk[2], pk[3]);
      *(uint4*)((char*)outp + (((size_t)wavei << 8) + ((uint)ln << 4))) = sv;
    }
  }
}

// ---------------- W -> fragment-major bf16 repack ----------------
// lane l holds W[k = kt*32 + (l>>4)*4 + (j&3) + 16*(j>>2)][col = nt*16 + (l&15)]

template <int KT, int NT>
__global__ void k_prep_w(const float* __restrict__ W, ushort* __restrict__ WF) {
  int tid = blockIdx.x * 256 + threadIdx.x;
  if (tid >= KT * NT * 64) return;
  int l  = tid & 63;
  int nt = (tid >> 6) % NT;
  int kt = tid / (64 * NT);
  int colc = nt * 16 + (l & 15);
  int kbase = kt * 32 + (l >> 4) * 4;
  ushort v[8];
  #pragma unroll
  for (int j = 0; j < 8; ++j) {
    int k = kbase + (j & 3) + 16 * (j >> 2);
    __hip_bfloat16 h = __float2bfloat16(W[(size_t)k * (NT * 16) + colc]);
    v[j] = *(ushort*)&h;
  }
  uint4 pk;
  pk.x = (uint)v[0] | ((uint)v[1] << 16);
  pk.y = (uint)v[2] | ((uint)v[3] << 16);
  pk.z = (uint)v[4] | ((uint)v[5] << 16);
  pk.w = (uint)v[6] | ((uint)v[7] << 16);
  *(uint4*)(WF + (size_t)tid * 8) = pk;
}

// ---------------- wave-N-specialized MFMA GEMM ----------------
// Block = 256 threads (4 waves), BM = 128 rows. Wave w owns its N-slice and preloads
// its W fragments into registers. mfma(A=Wfrag, B=Xfrag): lane&15 = X-row,
// (lane>>4)*4+reg = output features -> packed 8B bf16 stores.

template <int KT, int NTW, bool OUTBF16, bool BIASRELU>
__global__ __launch_bounds__(256) void k_gemm_wspec(const ushort* __restrict__ A,
                                                    const ushort* __restrict__ WF,
                                                    const float* __restrict__ bias,
                                                    void* __restrict__ Cout, int n) {
  constexpr int K   = KT * 32;
  constexpr int NT  = NTW * 4;
  constexpr int N   = NT * 16;
  constexpr int CPR = K / 8;                   // 16B chunks per row
  __shared__ short lds[128 * CPR * 8];

  int tid = threadIdx.x;
  int r0 = blockIdx.x * 128;
  int l  = tid & 63;
  int w  = tid >> 6;
  int hi = l >> 4;

  // preload this wave's W-slice into registers (independent of LDS staging)
  bf16x8 wreg[KT * NTW];
  #pragma unroll
  for (int kt = 0; kt < KT; ++kt)
    #pragma unroll
    for (int nt = 0; nt < NTW; ++nt)
      wreg[kt * NTW + nt] =
          *(const bf16x8*)(WF + ((size_t)(kt * NT + w * NTW + nt) * 64 + l) * 8);

  // bias for this wave's feature slice
  float4 bb[NTW];
  if (BIASRELU) {
    #pragma unroll
    for (int nt = 0; nt < NTW; ++nt)
      bb[nt] = *(const float4*)(bias + (w * NTW + nt) * 16 + hi * 4);
  }

  // stage A tile (coalesced 16B loads, XOR-swizzled 16B chunks)
  #pragma unroll
  for (int p = 0; p < (128 * CPR) / 256; ++p) {
    int idx = p * 256 + tid;
    int row = idx / CPR, c = idx % CPR;
    uint4 v = make_uint4(0u, 0u, 0u, 0u);
    if (r0 + row < n) v = *(const uint4*)(A + (size_t)(r0 + row) * K + c * 8);
    *(uint4*)(&lds[row * CPR * 8 + ((c ^ (row & 15))) * 8]) = v;
  }
  __syncthreads();

  int sw = l & 15;
  #pragma unroll
  for (int s = 0; s < 8; ++s) {
    int rowl = s * 16 + (l & 15);
    bf16x8 xf[KT];
    #pragma unroll
    for (int kt = 0; kt < KT; ++kt) {
      int c0 = kt * 4 + (hi >> 1);
      int within = (hi & 1) * 4;
      bf16x4 lo = *(const bf16x4*)(&lds[rowl * CPR * 8 + (c0 ^ sw) * 8 + within]);
      bf16x4 hx = *(const bf16x4*)(&lds[rowl * CPR * 8 + ((c0 + 2) ^ sw) * 8 + within]);
      bf16x8 a;
      a[0] = lo[0]; a[1] = lo[1]; a[2] = lo[2]; a[3] = lo[3];
      a[4] = hx[0]; a[5] = hx[1]; a[6] = hx[2]; a[7] = hx[3];
      xf[kt] = a;
    }

    f32x4 acc[NTW];
    #pragma unroll
    for (int nt = 0; nt < NTW; ++nt) acc[nt] = f32x4{0.f, 0.f, 0.f, 0.f};
    #pragma unroll
    for (int nt = 0; nt < NTW; ++nt)
      #pragma unroll
      for (int kt = 0; kt < KT; ++kt)
        acc[nt] = __builtin_amdgcn_mfma_f32_16x16x32_bf16(wreg[kt * NTW + nt], xf[kt],
                                                          acc[nt], 0, 0, 0);

    int grow = r0 + s * 16 + (l & 15);
    if (grow < n) {
      #pragma unroll
      for (int nt = 0; nt < NTW; ++nt) {
        int f0 = (w * NTW + nt) * 16 + hi * 4;
        float v0 = acc[nt][0], v1 = acc[nt][1], v2 = acc[nt][2], v3 = acc[nt][3];
        if (BIASRELU) {
          v0 = fmaxf(v0 + bb[nt].x, 0.0f);
          v1 = fmaxf(v1 + bb[nt].y, 0.0f);
          v2 = fmaxf(v2 + bb[nt].z, 0.0f);
          v3 = fmaxf(v3 + bb[nt].w, 0.0f);
        }
        if (OUTBF16) {
          ushort o[4];
          __hip_bfloat16 h;
          h = __float2bfloat16(v0); o[0] = *(ushort*)&h;
          h = __float2bfloat16(v1); o[1] = *(ushort*)&h;
          h = __float2bfloat16(v2); o[2] = *(ushort*)&h;
          h = __float2bfloat16(v3); o[3] = *(ushort*)&h;
          uint2 pk;
          pk.x = (uint)o[0] | ((uint)o[1] << 16);
          pk.y = (uint)o[2] | ((uint)o[3] << 16);
          *(uint2*)((ushort*)Cout + (size_t)grow * N + f0) = pk;
        } else {
          f32x4 pk = {v0, v1, v2, v3};
          *(f32x4*)((float*)Cout + (size_t)grow * N + f0) = pk;
        }
      }
    }
  }
}

// ---------------- output ----------------

__global__ void k_fillout(float* __restrict__ out, int total) {
  int i = blockIdx.x * blockDim.x + threadIdx.x;
  if (i < total) out[i] = -0.69314718055994531f;
}

// self-loop lives in the CSR now: plain weighted sum over all slots
__global__ void k_agg3(const float* __restrict__ h3, const int* __restrict__ rp,
                       const int2* __restrict__ cw, const float* __restrict__ b3,
                       const int* __restrict__ l2g, float* __restrict__ out, int n) {
  int i = blockIdx.x * blockDim.x + threadIdx.x;
  if (i >= n) return;
  float a0 = 0.f, a1 = 0.f;
  int e0 = rp[i], e1 = rp[i + 1];
  for (int e = e0; e < e1; ++e) {
    int2 c = cw[e];
    float w = __int_as_float(c.y);
    a0 = fmaf(w, h3[(size_t)c.x * 2 + 0], a0);
    a1 = fmaf(w, h3[(size_t)c.x * 2 + 1], a1);
  }
  a0 += b3[0];
  a1 += b3[1];
  float m = fmaxf(a0, a1);
  float lse = m + logf(expf(a0 - m) + expf(a1 - m));
  int g = l2g[i];
  out[(size_t)g * 2 + 0] = a0 - lse;
  out[(size_t)g * 2 + 1] = a1 - lse;
}

// ---------------- launch ----------------

extern "C" void kernel_launch(void* const* d_in, const int* in_sizes, int n_in,
                              void* d_out, int out_size, void* d_ws, size_t ws_size,
                              hipStream_t stream) {
  const float* building_x = (const float*)d_in[0];
  const int*   l2g        = (const int*)d_in[1];
  const int*   esrc       = (const int*)d_in[2];
  const int*   edst       = (const int*)d_in[3];
  const float* W1 = (const float*)d_in[4];
  const float* b1 = (const float*)d_in[5];
  const float* W2 = (const float*)d_in[6];
  const float* b2 = (const float*)d_in[7];
  const float* W3 = (const float*)d_in[8];
  const float* b3 = (const float*)d_in[9];
  float* out = (float*)d_out;

  const int n_total = in_sizes[0] / F_IN;
  const int n_sub   = in_sizes[1];
  const int E       = in_sizes[2];
  const int Etot    = E + n_sub;          // edges + self-loops
  const int nb      = (n_sub + 255) / 256;

  // ---- workspace (bf16 128-wide tensors, aliasing across phases) ----
  // xsub: input bf16 table (dead after agg1); xt: agg1 out (dead after gemm1,
  // reused by h2b); x1: gemm1 out.
  char* base = (char*)d_ws;
  auto al = [](size_t x) { return (x + 255) & ~(size_t)255; };
  size_t t128 = al((size_t)n_sub * 128 * 2);
  ushort* xsub = (ushort*)base;
  ushort* xt   = (ushort*)(base + t128);
  ushort* x1   = (ushort*)(base + 2 * t128);
  ushort* h2b  = xt;
  size_t off = 2 * t128 + al((size_t)n_sub * 256 * 2);
  auto alloc = [&](size_t bytes) -> void* {
    void* p = base + off;
    off += al(bytes);
    return p;
  };
  float* h3   = (float*)alloc((size_t)n_sub * 2 * 4);
  int*   cnt  = (int*)alloc((size_t)n_sub * 4);
  int*   fill = (int*)alloc((size_t)n_sub * 4);
  int*   rp   = (int*)alloc((size_t)(n_sub + 1) * 4);
  float* dis  = (float*)alloc((size_t)n_sub * 4);
  int2*  cw   = (int2*)alloc((size_t)Etot * 8);
  int*   bsum = (int*)alloc((size_t)nb * 4);
  ushort* w1f = (ushort*)alloc((size_t)128 * 256 * 2);
  ushort* w2f = (ushort*)alloc((size_t)256 * 128 * 2);
  (void)ws_size; (void)n_in; (void)out_size;

  const int B = 256;

  // weight repack + input bf16 conversion (independent of CSR)
  k_prep_w<4, 16><<<16, 256, 0, stream>>>(W1, w1f);
  k_prep_w<8, 8><<<16, 256, 0, stream>>>(W2, w2f);
  k_tobf16<<<(n_sub * 32 + B - 1) / B, B, 0, stream>>>(building_x, l2g, xsub, n_sub);

  // CSR build (self-loops included)
  k_one<<<(n_sub + B - 1) / B, B, 0, stream>>>(cnt, n_sub);
  k_count<<<(E + B - 1) / B, B, 0, stream>>>(edst, cnt, E);
  k_scan1<<<nb, 256, 0, stream>>>(cnt, rp, bsum, dis, fill, n_sub);
  k_scan2<<<1, 1024, 0, stream>>>(bsum, nb);
  k_scan3<<<(n_sub + B - 1) / B, B, 0, stream>>>(rp, bsum, n_sub, Etot);
  int fillGrid = ((E > n_sub ? E : n_sub) + B - 1) / B;
  k_fill_csr<<<fillGrid, B, 0, stream>>>(esrc, edst, rp, fill, dis, cw, E, n_sub);

  int aggBlocks  = (n_sub + 3) / 4;       // 4 waves / 256-thread block
  int gemmBlocks = (n_sub + 127) / 128;   // BM=128

  // Layer 1: aggregate (bf16 gather) -> bf16 xt, MFMA GEMM + bias + relu -> bf16 x1
  k_aggb<false, false><<<aggBlocks, B, 0, stream>>>(xsub, rp, cw, nullptr, nullptr,
                                                    xt, nullptr, n_sub);
  k_gemm_wspec<4, 4, true, true><<<gemmBlocks, 256, 0, stream>>>(xt, w1f, b1, x1, n_sub);

  // Layer 2: MFMA GEMM (x1 @ W2) -> bf16 h2b, then fused aggregate+bias+relu+W3 -> h3
  k_gemm_wspec<8, 2, true, false><<<gemmBlocks, 256, 0, stream>>>(x1, w2f, nullptr, h2b, n_sub);
  k_aggb<true, true><<<aggBlocks, B, 0, stream>>>(h2b, rp, cw, b2, W3,
                                                  nullptr, h3, n_sub);

  // Layer 3: fill output, aggregate h3 + bias + log_softmax scatter
  k_fillout<<<(2 * n_total + B - 1) / B, B, 0, stream>>>(out, 2 * n_total);
  k_agg3<<<(n_sub + B - 1) / B, B, 0, stream>>>(h3, rp, cw, b3, l2g, out, n_sub);
}